// Round 10
// baseline (100.445 us; speedup 1.0000x reference)
//
#include <hip/hip_runtime.h>

// ---------------------------------------------------------------------------
// KAN conv layer: out[b,o,i,j] = sum_{c,p} silu(patch)*bw[o,c,p]
//                              + sum_{c,p,g} Bspline_g(patch)*sw[o,c,p,g]*sc[o,c,p]
// B=16 CIN=32 COUT=64 H=W=64 K=3 -> Ho=Wo=62, P=9, G+k=8 bases
// Implicit GEMM. Spline K=2304 fp8-MX; silu K=288 bf16.
// R9 (100.2us): MX supersteps but feature frags = 8B-run gathers (b64 x4,
//     ~4-way bank conflicts) -> LDS-issue-bound ~24us.
// R10: tap-major k-order: superstep (tap,ss) covers c=16ss..16ss+15, g=0..7.
//     Lane fragment = 32 CONTIGUOUS bytes of one pixel's c-block ->
//     2x ds_read_b128, conflict-free. Fspl layout [b][y][cblk16][x][16B].
//     2304 = 18x128 exact (no leftover step). Features staged per c-half
//     (48 KB, restage hidden under silu phase between passes); weights dbuf
//     8 KB/tap. Silu branch byte-identical to R9.
// ---------------------------------------------------------------------------

typedef short v8s __attribute__((ext_vector_type(8)));
typedef float v4f __attribute__((ext_vector_type(4)));
typedef int   v4i __attribute__((ext_vector_type(4)));
typedef int   v8i __attribute__((ext_vector_type(8)));

#define FSPL8_OFF   0u             // [b][y][blk16][x64][16B] = 16,777,216
#define FSILU_OFF   16777472u      // 4,194,304
#define WMX_OFF     20972032u      // [tap9][ss2][u8][lane64][16B] = 147,456
#define WPACKS_OFF  21119488u      // [sp9][ot4][lane64][e8] bf16 = 36,864

#define SCALE1 0x7F7F7F7Fu         // E8M0 127 = 1.0

__device__ __forceinline__ unsigned short f2bf(float f) {
  unsigned int u = __float_as_uint(f);
  u += 0x7fffu + ((u >> 16) & 1u);
  return (unsigned short)(u >> 16);
}

// ---- kernel 1: fused features: fp8 bases (c-block layout) + bf16 silu ------
__global__ __launch_bounds__(256) void k_feat(const float* __restrict__ x,
                                              unsigned char* __restrict__ ws) {
  const int bid = blockIdx.x;              // b*64 + y
  const int b = bid >> 6, y = bid & 63;
  const int t = threadIdx.x;
  const int xx = t & 63, cg = t >> 6;      // cg: 8-channel group 0..3
  unsigned short h[8];
  uint2 sp[8];
#pragma unroll
  for (int k = 0; k < 8; ++k) {
    const int c = cg * 8 + k;
    const float v = x[(((size_t)(b * 32 + c) * 64 + y) * 64) + xx];
    h[k] = f2bf(v / (1.0f + __expf(-v)));
    float bb[11];
#pragma unroll
    for (int i = 0; i < 11; ++i) {
      float t0 = -2.2f + 0.4f * i;
      bb[i] = (v >= t0 && v < t0 + 0.4f) ? 1.0f : 0.0f;
    }
#pragma unroll
    for (int j = 1; j <= 3; ++j) {
      float rj = 1.0f / (0.4f * j);
#pragma unroll
      for (int i = 0; i + j < 11; ++i) {
        float ti = -2.2f + 0.4f * i;
        bb[i] = (v - ti) * rj * bb[i] + ((ti + 0.4f * (j + 1)) - v) * rj * bb[i + 1];
      }
    }
    unsigned w0 = __builtin_amdgcn_cvt_pk_fp8_f32(bb[0], bb[1], 0, false);
    w0 = __builtin_amdgcn_cvt_pk_fp8_f32(bb[2], bb[3], w0, true);
    unsigned w1 = __builtin_amdgcn_cvt_pk_fp8_f32(bb[4], bb[5], 0, false);
    w1 = __builtin_amdgcn_cvt_pk_fp8_f32(bb[6], bb[7], w1, true);
    sp[k].x = w0; sp[k].y = w1;
  }
  // spline: 4x 16B stores, block blk = cg*4+m holds channels {2m, 2m+1} of cg
#pragma unroll
  for (int m = 0; m < 4; ++m) {
    uint4 v;
    v.x = sp[2 * m].x;     v.y = sp[2 * m].y;
    v.z = sp[2 * m + 1].x; v.w = sp[2 * m + 1].y;
    *(uint4*)(ws + FSPL8_OFF +
              ((size_t)((b * 64 + y) * 16 + cg * 4 + m)) * 1024 + xx * 16) = v;
  }
  uint4 s;
  s.x = (unsigned)h[0] | ((unsigned)h[1] << 16);
  s.y = (unsigned)h[2] | ((unsigned)h[3] << 16);
  s.z = (unsigned)h[4] | ((unsigned)h[5] << 16);
  s.w = (unsigned)h[6] | ((unsigned)h[7] << 16);
  *(uint4*)(ws + FSILU_OFF + (size_t)(b * 4096 + y * 64 + xx) * 64 + cg * 16) = s;
}

// ---- kernel 2: pack weights (MX fp8 tap-major; silu bf16) ------------------
__global__ __launch_bounds__(256) void k_wpack(const float* __restrict__ bw,
                                               const float* __restrict__ sw,
                                               const float* __restrict__ sc,
                                               unsigned char* __restrict__ ws) {
  int tid = blockIdx.x * 256 + threadIdx.x;
  if (tid >= 165888) return;
  if (tid < 147456) {                      // WMX [tap][ss][u=ot*2+pc][lane][16]
    int hh = tid & 15, lane = (tid >> 4) & 63, u = (tid >> 10) & 7;
    int ss = (tid >> 13) & 1, tau = tid >> 14;           // 0..8
    int ot = u >> 1, pc = u & 1, q = lane >> 4;
    int m = pc * 16 + hh;                  // byte index 0..31 = k-sub
    int c = 16 * ss + 4 * q + (m >> 3), g = m & 7;
    int o = (ot << 4) + (lane & 15);
    float val = sw[((size_t)(o * 32 + c) * 9 + tau) * 8 + g] *
                sc[(size_t)(o * 32 + c) * 9 + tau];
    ws[WMX_OFF + tid] =
        (unsigned char)(__builtin_amdgcn_cvt_pk_fp8_f32(val, 0.f, 0, false) & 0xff);
  } else {                                 // silu bf16: [sp9][ot4][lane64][e8]
    int t2 = tid - 147456;
    int e = t2 & 7, lane = (t2 >> 3) & 63, ot = (t2 >> 9) & 3, sp = t2 >> 11;
    int o = (ot << 4) + (lane & 15);
    int cc = ((lane >> 4) << 3) + e;
    float val = bw[(size_t)(o * 32 + cc) * 9 + sp];
    *(unsigned short*)(ws + WPACKS_OFF + (size_t)t2 * 2) = f2bf(val);
  }
}

// ---- async 16B global -> LDS (lds dest = wave-uniform base + lane*16) ------
__device__ __forceinline__ void ld16(unsigned char* ldsp, const unsigned char* gp) {
  __builtin_amdgcn_global_load_lds(
      (const __attribute__((address_space(1))) unsigned int*)gp,
      (__attribute__((address_space(3))) unsigned int*)ldsp, 16, 0, 0);
}

// ---- kernel 3: implicit GEMM, tap-major MX, all-b128 fragments -------------
// Block: 8 waves = (r = w>>1, oh = w&1), 256 blocks (1/CU). Two passes over
// ss (c-halves); per pass 9 taps, each = 1 MX superstep (K=128) per wave:
// 8 MFMA, 4 w-b128 + 8 f-b128. Weights dbuf 8 KB/tap; features 48 KB/pass
// (restage hidden under silu phase). Silu branch = R9 bytes.
__global__ __launch_bounds__(512) void k_gemm(const unsigned char* __restrict__ ws,
                                              float* __restrict__ out) {
  __shared__ __align__(16) unsigned char wmx[2][8192];
  __shared__ __align__(16) unsigned char feat[49664];     // 48 KB + pad
  __shared__ __align__(16) unsigned char wsil[36864];
  __shared__ __align__(16) unsigned char fsil[25088];

  const int blk = blockIdx.x;              // b*16 + ig
  const int b = blk >> 4, ig = blk & 15;
  const int i0 = ig * 4;
  const int tid = threadIdx.x;
  const int wave = tid >> 6, lane = tid & 63;
  const int q = lane >> 4, ln = lane & 15;
  const int r = wave >> 1, oh = wave & 1;
  const int i = i0 + r;

  auto stage_w = [&](int tau, int ss, int bi) {   // 8 chunks, 1/wave
    ld16(&wmx[bi][wave * 1024],
         ws + WMX_OFF + (size_t)((tau * 2 + ss) * 8 + wave) * 1024 + lane * 16);
  };
  auto stage_feat = [&](int ss) {                 // 48 chunks: (yrel, blk=wave)
#pragma unroll
    for (int it = 0; it < 6; ++it) {
      const int y = min(i0 + it, 63);
      ld16(&feat[(it * 8 + wave) * 1024],
           ws + FSPL8_OFF + (size_t)((b * 64 + y) * 16 + 8 * ss + wave) * 1024 + lane * 16);
    }
  };
  auto stage_silu = [&]() {                       // 60 chunks
#pragma unroll
    for (int it = 0; it < 8; ++it) {
      const int u = wave + it * 8;
      if (u < 36) {
        ld16(&wsil[u * 1024], ws + WPACKS_OFF + (size_t)u * 1024 + lane * 16);
      } else if (u < 60) {
        const int v = u - 36;
        const int rr = v >> 2, p4 = v & 3;
        const int y = min(i0 + rr, 63);
        ld16(&fsil[v * 1024],
             ws + FSILU_OFF + (size_t)(b * 64 + y) * 4096 +
                 (p4 * 16 + (lane >> 2)) * 64 + ((lane & 3) ^ ((lane >> 2) & 3)) * 16);
      }
    }
  };

  v4f acc[2][4];
#pragma unroll
  for (int a = 0; a < 2; ++a)
#pragma unroll
    for (int c = 0; c < 4; ++c) acc[a][c] = (v4f){0.f, 0.f, 0.f, 0.f};

  auto superstep = [&](int tau, int bi) {
    const int di = tau / 3, dj = tau - 3 * di;
    union { v8i v; v4i h[2]; } wf[2], ff[4];
#pragma unroll
    for (int tt = 0; tt < 2; ++tt)
#pragma unroll
      for (int pc = 0; pc < 2; ++pc)
        wf[tt].h[pc] = *(const v4i*)(&wmx[bi][((oh * 2 + tt) * 2 + pc) * 1024 + lane * 16]);
#pragma unroll
    for (int pt = 0; pt < 4; ++pt) {
      const int xx = ln + dj + 16 * pt;
#pragma unroll
      for (int pc = 0; pc < 2; ++pc)
        ff[pt].h[pc] = *(const v4i*)(&feat[((r + di) * 8 + 2 * q + pc) * 1024 + xx * 16]);
    }
#pragma unroll
    for (int tt = 0; tt < 2; ++tt)
#pragma unroll
      for (int pt = 0; pt < 4; ++pt)
        acc[tt][pt] = __builtin_amdgcn_mfma_scale_f32_16x16x128_f8f6f4(
            wf[tt].v, ff[pt].v, acc[tt][pt], 0, 0, 0, SCALE1, 0, SCALE1);
  };

  stage_w(0, 0, 0);
  stage_feat(0);
  stage_silu();
  __syncthreads();

  // ---- pass 0: ss = 0 ------------------------------------------------------
#pragma unroll 1
  for (int t = 0; t < 9; ++t) {
    if (t < 8) stage_w(t + 1, 0, (t + 1) & 1);
    superstep(t, t & 1);
    __syncthreads();
  }

  // ---- interlude: restage features (ss=1) hidden under silu phase ----------
  stage_feat(1);
  stage_w(0, 1, 1);
#pragma unroll
  for (int e = 0; e < 9; ++e) {
    const int di = e / 3, dj = e % 3;
    v8s wb2[2], fb2[4];
#pragma unroll
    for (int tt = 0; tt < 2; ++tt)
      wb2[tt] = *(const v8s*)(&wsil[0] + e * 4096 + (oh * 2 + tt) * 1024 + lane * 16);
    const int xb = dj + ln;
    const int sbase = (r + di) * 4096 + xb * 64 + ((q ^ (xb & 3)) * 16);
#pragma unroll
    for (int pt = 0; pt < 4; ++pt)
      fb2[pt] = *(const v8s*)(&fsil[0] + sbase + pt * 1024);
#pragma unroll
    for (int tt = 0; tt < 2; ++tt)
#pragma unroll
      for (int pt = 0; pt < 4; ++pt)
        acc[tt][pt] = __builtin_amdgcn_mfma_f32_16x16x32_bf16(
            wb2[tt], fb2[pt], acc[tt][pt], 0, 0, 0);
  }
  __syncthreads();                         // feat(ss=1) + w(tap0,ss1) landed

  // ---- pass 1: ss = 1 ------------------------------------------------------
#pragma unroll 1
  for (int t = 0; t < 9; ++t) {
    if (t < 8) stage_w(t + 1, 1, t & 1);
    superstep(t, (t + 1) & 1);
    __syncthreads();
  }

  // ---- epilogue: C/D layout col(n=j)=lane&15, row(m=o)=q*4+reg -------------
  if (i < 62) {
#pragma unroll
    for (int tt = 0; tt < 2; ++tt)
#pragma unroll
      for (int pt = 0; pt < 4; ++pt) {
        const int j = pt * 16 + ln;
        if (j < 62) {
#pragma unroll
          for (int rr = 0; rr < 4; ++rr) {
            const int o = (oh * 2 + tt) * 16 + q * 4 + rr;
            out[(((size_t)b * 64 + o) * 62 + i) * 62 + j] = acc[tt][pt][rr];
          }
        }
      }
  }
}

extern "C" void kernel_launch(void* const* d_in, const int* in_sizes, int n_in,
                              void* d_out, int out_size, void* d_ws, size_t ws_size,
                              hipStream_t stream) {
  const float* x  = (const float*)d_in[0];
  const float* bw = (const float*)d_in[1];
  const float* sw = (const float*)d_in[2];
  const float* sc = (const float*)d_in[3];
  unsigned char* ws = (unsigned char*)d_ws;
  float* out = (float*)d_out;

  hipLaunchKernelGGL(k_feat,  dim3(1024), dim3(256), 0, stream, x, ws);
  hipLaunchKernelGGL(k_wpack, dim3(648),  dim3(256), 0, stream, bw, sw, sc, ws);
  hipLaunchKernelGGL(k_gemm,  dim3(256),  dim3(512), 0, stream, ws, out);
}